// Round 1
// baseline (212.563 us; speedup 1.0000x reference)
//
#include <hip/hip_runtime.h>

// DeformUnfold: deformable-conv im2col.
// x:      [B=8, C=64, H=128, W=128] f32
// offset: [B, 2*K=18, H, W] f32   (channel order: k-major, then (y,x))
// out:    [B, C*K, Ho*Wo] f32, Ho=Wo=128 (stride1,pad1,dil1,k3x3)
//
// One thread per (b, k, ho, wo). Sampling coords are channel-independent,
// so compute 4 corner indices + weights once, loop over all C channels.

constexpr int Bc = 8;
constexpr int Cc = 64;
constexpr int Hc = 128;
constexpr int Wc = 128;
constexpr int KHc = 3, KWc = 3, Kc = 9;
constexpr int PADc = 1;
constexpr int HWc = Hc * Wc;          // 16384
constexpr int HoWoc = HWc;            // same spatial size

__global__ __launch_bounds__(256) void deform_unfold_kernel(
    const float* __restrict__ x,
    const float* __restrict__ offset,
    float* __restrict__ out)
{
    int tid = blockIdx.x * blockDim.x + threadIdx.x;
    // tid = ((b*K + k)*Ho + ho)*Wo + wo
    int wo = tid & (Wc - 1);
    int t1 = tid >> 7;          // / Wo
    int ho = t1 & (Hc - 1);
    int t2 = t1 >> 7;           // / Ho
    int k  = t2 % Kc;
    int b  = t2 / Kc;

    int sp = (ho << 7) | wo;    // ho*Wo + wo

    // offset channels: [B, K, 2, Ho, Wo]
    const float* offb = offset + ((size_t)b * (2 * Kc)) * HoWoc;
    float offy = offb[(size_t)(2 * k + 0) * HoWoc + sp];
    float offx = offb[(size_t)(2 * k + 1) * HoWoc + sp];

    float py = (float)(k / KWc + ho - PADc) + offy;
    float px = (float)(k % KWc + wo - PADc) + offx;

    float y0f = floorf(py);
    float x0f = floorf(px);
    float ly = py - y0f, lx = px - x0f;
    float hy = 1.0f - ly, hx = 1.0f - lx;

    int y0 = (int)y0f, x0 = (int)x0f;
    int y1 = y0 + 1,   x1 = x0 + 1;

    bool vy0 = (y0 >= 0) & (y0 < Hc);
    bool vy1 = (y1 >= 0) & (y1 < Hc);
    bool vx0 = (x0 >= 0) & (x0 < Wc);
    bool vx1 = (x1 >= 0) & (x1 < Wc);

    float w00 = hy * hx * ((vy0 & vx0) ? 1.0f : 0.0f);
    float w01 = hy * lx * ((vy0 & vx1) ? 1.0f : 0.0f);
    float w10 = ly * hx * ((vy1 & vx0) ? 1.0f : 0.0f);
    float w11 = ly * lx * ((vy1 & vx1) ? 1.0f : 0.0f);

    int y0c = min(max(y0, 0), Hc - 1);
    int y1c = min(max(y1, 0), Hc - 1);
    int x0c = min(max(x0, 0), Wc - 1);
    int x1c = min(max(x1, 0), Wc - 1);

    int i00 = (y0c << 7) + x0c;
    int i01 = (y0c << 7) + x1c;
    int i10 = (y1c << 7) + x0c;
    int i11 = (y1c << 7) + x1c;

    const float* xb = x + (size_t)b * Cc * HWc;
    // out index: ((b*C + c)*K + k)*HoWo + sp
    float* ob = out + ((size_t)b * Cc * Kc + k) * (size_t)HoWoc + sp;

#pragma unroll 4
    for (int c = 0; c < Cc; ++c) {
        const float* xp = xb + (size_t)c * HWc;
        float v = w00 * xp[i00] + w01 * xp[i01]
                + w10 * xp[i10] + w11 * xp[i11];
        ob[(size_t)c * (Kc * HoWoc)] = v;
    }
}

extern "C" void kernel_launch(void* const* d_in, const int* in_sizes, int n_in,
                              void* d_out, int out_size, void* d_ws, size_t ws_size,
                              hipStream_t stream) {
    const float* x      = (const float*)d_in[0];
    const float* offset = (const float*)d_in[1];
    float* out          = (float*)d_out;

    int total = Bc * Kc * HoWoc;          // 1,179,648 threads
    int block = 256;
    int grid  = (total + block - 1) / block;
    deform_unfold_kernel<<<grid, block, 0, stream>>>(x, offset, out);
}

// Round 2
// 208.107 us; speedup vs baseline: 1.0214x; 1.0214x over previous
//
#include <hip/hip_runtime.h>

// DeformUnfold: deformable-conv im2col.
// x:      [B=8, C=64, H=128, W=128] f32
// offset: [B, 2*K=18, H, W] f32   (channel order: k-major, then (y,x))
// out:    [B, C*K, Ho*Wo] f32, Ho=Wo=128 (stride1,pad1,dil1,k3x3)
//
// R1: one thread per (b, channel-group, sp) computing ALL 9 taps for 8
// channels. 9 taps share a 3x3+jitter neighborhood -> L1 reuse across k;
// 36 independent gathers in flight per channel iteration -> latency hiding.

constexpr int Bc = 8;
constexpr int Cc = 64;
constexpr int Hc = 128;
constexpr int Wc = 128;
constexpr int Kc = 9;
constexpr int HWc = Hc * Wc;          // 16384
constexpr int HoWoc = HWc;
constexpr int CPT = 8;                // channels per thread
constexpr int NCG = Cc / CPT;         // 8 channel groups

__global__ __launch_bounds__(256) void deform_unfold_k9(
    const float* __restrict__ x,
    const float* __restrict__ offset,
    float* __restrict__ out)
{
    int tid = blockIdx.x * blockDim.x + threadIdx.x;
    int sp   = tid & (HWc - 1);       // spatial index, contiguous across lanes
    int rest = tid >> 14;
    int cg   = rest & (NCG - 1);
    int b    = rest >> 3;             // log2(NCG) = 3

    int wo = sp & (Wc - 1);
    int ho = sp >> 7;

    const float* offb = offset + (size_t)b * (2 * Kc) * HoWoc + sp;

    int   idx[Kc][4];
    float w[Kc][4];
#pragma unroll
    for (int k = 0; k < Kc; ++k) {
        float offy = offb[(size_t)(2 * k + 0) * HoWoc];
        float offx = offb[(size_t)(2 * k + 1) * HoWoc];

        float py = (float)(k / 3 + ho - 1) + offy;
        float px = (float)(k % 3 + wo - 1) + offx;

        float y0f = floorf(py), x0f = floorf(px);
        float ly = py - y0f, lx = px - x0f;
        float hy = 1.0f - ly, hx = 1.0f - lx;

        int y0 = (int)y0f, x0 = (int)x0f;
        int y1 = y0 + 1,   x1 = x0 + 1;

        bool vy0 = (unsigned)y0 < (unsigned)Hc;
        bool vy1 = (unsigned)y1 < (unsigned)Hc;
        bool vx0 = (unsigned)x0 < (unsigned)Wc;
        bool vx1 = (unsigned)x1 < (unsigned)Wc;

        w[k][0] = hy * hx * ((vy0 & vx0) ? 1.0f : 0.0f);
        w[k][1] = hy * lx * ((vy0 & vx1) ? 1.0f : 0.0f);
        w[k][2] = ly * hx * ((vy1 & vx0) ? 1.0f : 0.0f);
        w[k][3] = ly * lx * ((vy1 & vx1) ? 1.0f : 0.0f);

        int y0c = min(max(y0, 0), Hc - 1);
        int y1c = min(max(y1, 0), Hc - 1);
        int x0c = min(max(x0, 0), Wc - 1);
        int x1c = min(max(x1, 0), Wc - 1);

        idx[k][0] = (y0c << 7) + x0c;
        idx[k][1] = (y0c << 7) + x1c;
        idx[k][2] = (y1c << 7) + x0c;
        idx[k][3] = (y1c << 7) + x1c;
    }

    const float* xb = x + ((size_t)b * Cc + (size_t)cg * CPT) * HWc;
    float* ob = out + (((size_t)b * Cc + (size_t)cg * CPT) * Kc) * (size_t)HoWoc + sp;

#pragma unroll 1
    for (int c = 0; c < CPT; ++c) {
        const float* xp = xb + (size_t)c * HWc;
        float v[Kc];
#pragma unroll
        for (int k = 0; k < Kc; ++k) {
            v[k] = w[k][0] * xp[idx[k][0]] + w[k][1] * xp[idx[k][1]]
                 + w[k][2] * xp[idx[k][2]] + w[k][3] * xp[idx[k][3]];
        }
#pragma unroll
        for (int k = 0; k < Kc; ++k) {
            ob[((size_t)c * Kc + k) * HoWoc] = v[k];
        }
    }
}

extern "C" void kernel_launch(void* const* d_in, const int* in_sizes, int n_in,
                              void* d_out, int out_size, void* d_ws, size_t ws_size,
                              hipStream_t stream) {
    const float* x      = (const float*)d_in[0];
    const float* offset = (const float*)d_in[1];
    float* out          = (float*)d_out;

    int total = Bc * NCG * HWc;          // 1,048,576 threads
    int block = 256;
    int grid  = total / block;           // 4096 blocks
    deform_unfold_k9<<<grid, block, 0, stream>>>(x, offset, out);
}